// Round 16
// baseline (162.357 us; speedup 1.0000x reference)
//
#include <hip/hip_runtime.h>
#include <math.h>

#define BB   256
#define NPER 256
#define NN   (BB*NPER)
#define HH   128
#define DDIM 384
#define KK   30
#define SPD  388
#define ASTR 264          // 66 dwords -> 2-way bank alias (free)
#define ABYTES 67584
#define XSTR 384          // x holds all 3 layers (paired cols, sort-invariant)

#define NSOFF  67584
#define NDOFF  68608
#define SCROFF 69632      // 3072B: degi, dego, z_s
#define SMEM_SZ 72704     // <= 80K -> 2 blocks/CU

typedef _Float16 half8 __attribute__((ext_vector_type(8)));
typedef float f32x16 __attribute__((ext_vector_type(16)));

__device__ __forceinline__ float ftanh(float x) {
    float ax = fabsf(x);
    float e = __expf(-2.f * ax);
    float r = (1.f - e) / (1.f + e);
    return copysignf(r, x);
}

// swap bits 2<->3: MFMA k-group permutation (validated bit-exact r6-r15)
__device__ __forceinline__ int sig(int s) {
    return (s & ~12) | ((s & 4) << 1) | ((s & 8) >> 1);
}

// cross-lane xor exchange; DPP for 1/2/8 (VALU pipe), ds_swizzle 4/16, shfl 32.
// All xor<=16 stay within 32-lane groups (matches swizzle/DPP semantics).
template <int D>
__device__ __forceinline__ float shx(float v) {
    int xx = __float_as_int(v);
    int r;
    if constexpr (D == 1)       r = __builtin_amdgcn_update_dpp(0, xx, 0xB1, 0xF, 0xF, true);   // quad_perm [1,0,3,2]
    else if constexpr (D == 2)  r = __builtin_amdgcn_update_dpp(0, xx, 0x4E, 0xF, 0xF, true);   // quad_perm [2,3,0,1]
    else if constexpr (D == 8)  r = __builtin_amdgcn_update_dpp(0, xx, 0x128, 0xF, 0xF, true);  // row_ror:8 == xor8
    else if constexpr (D == 4)  r = __builtin_amdgcn_ds_swizzle(xx, 0x101F);                     // xor4
    else if constexpr (D == 16) r = __builtin_amdgcn_ds_swizzle(xx, 0x401F);                     // xor16
    else                        return __shfl_xor(v, D, 64);
    return __int_as_float(r);
}

// ============ kernel 1: GraphConv layers, feature-split (2 blocks/graph) ============
// block (g, half): 64 of 128 features, all 256 nodes, all 3 layers — columns are
// independent through the stack (agg[:,f]=A·h[:,f]; tanh/bias/norm per-column).
// 512 thr = 8 waves; LDS 72.7K -> 2 blocks/CU -> 4 waves/SIMD; regs ~120 <= 128.
__global__ __launch_bounds__(512, 4) void k_layers(
        const int* __restrict__ z, const int* __restrict__ src, const int* __restrict__ dst,
        const float* __restrict__ zt, const float* __restrict__ biases,
        float* __restrict__ x, float* __restrict__ nmaxP) {
    extern __shared__ char smem[];
    unsigned char* As = (unsigned char*)smem;          // 256 x 264 u8 (phase 0 only)
    char* HTH = smem;                                  // 64 rows x 512B f16 hi (overlays As)
    char* HTL = smem + 32768;                          // 64 rows x 512B f16 lo
    float* ns_s = (float*)(smem + NSOFF);
    float* nd_s = (float*)(smem + NDOFF);
    int*   scr  = (int*)(smem + SCROFF);
    int* degi = scr; int* dego = scr + 256; int* z_s = scr + 512;

    const int t = threadIdx.x;
    const int g = blockIdx.x >> 1, half = blockIdx.x & 1;
    const int vbase = g * NPER, F0 = half * 64;
    const int l31 = t & 31, hl = (t >> 5) & 1, rs = t >> 6;
    const int xorf = l31 << 4;
    const int aRow = (rs * 32 + l31) * ASTR;
    const int bR0  = l31 * 512;                        // ct=0 rows; ct=1 at +16384

    // ---------------- phase 0: build A (LDS) + histograms ----------------
    {
        int4 zz = {0, 0, 0, 0};
        for (int i = t; i < ABYTES / 16; i += 512) ((int4*)smem)[i] = zz;
    }
    if (t < 256) { degi[t] = 0; dego[t] = 0; z_s[t] = z[vbase + t]; }
    __syncthreads();
    for (int e = t; e < 4096; e += 512) {
        int s = src[g * 4096 + e] & 255;      // local ids by construction
        int d = dst[g * 4096 + e] & 255;
        atomicAdd(&dego[s], 1);
        atomicAdd(&degi[d], 1);
        int off = d * ASTR + sig(s);
        atomicAdd((unsigned*)(As + (off & ~3)), 1u << ((off & 3) * 8));
    }
    __syncthreads();
    if (t < 256) {
        ns_s[t] = rsqrtf((float)max(dego[t], 1));
        nd_s[t] = rsqrtf((float)max(degi[t], 1));
    }
    // h0 (unscaled) into C-layout registers: this block's 64 feats
    float h[2][16];
    #pragma unroll
    for (int ct = 0; ct < 2; ++ct) {
        #pragma unroll
        for (int r = 0; r < 16; ++r) {
            int d = rs * 32 + (r & 3) + 8 * (r >> 2) + 4 * hl;
            h[ct][r] = zt[(size_t)z_s[d] * HH + F0 + ct * 32 + l31];
        }
    }
    // A slice u8-packed into 32 regs (As LDS dies after this; HT overlays)
    uint2 A2[16];
    #pragma unroll
    for (int ks = 0; ks < 16; ++ks)
        A2[ks] = *(const uint2*)(As + aRow + ks * 16 + hl * 8);

    float rmax[16];
    const half8 k1024 = {(_Float16)1024.f, (_Float16)1024.f, (_Float16)1024.f, (_Float16)1024.f,
                         (_Float16)1024.f, (_Float16)1024.f, (_Float16)1024.f, (_Float16)1024.f};

    // ---------------- phase 1: 3 GraphConv layers, 2-term fp16 split MFMA ----------------
    for (int l = 0; l < 3; ++l) {
        float bias0 = biases[l * HH + F0 + l31];
        float bias1 = biases[l * HH + F0 + 32 + l31];
        f32x16 acc0 = {}, acc1 = {};

        __syncthreads();                      // prior kloop reads / A2 loads done
        // write BOTH split terms of (h * ns)
        #pragma unroll
        for (int ct = 0; ct < 2; ++ct) {
            int rowb = (ct * 32 + l31) * 512;
            #pragma unroll
            for (int qp = 0; qp < 2; ++qp) {
                union { _Float16 hx[8]; int4 u; } H, L;
                #pragma unroll
                for (int jj = 0; jj < 8; ++jj) {
                    int q = 2 * qp + (jj >> 2), j = jj & 3;
                    int r = 4 * q + j;
                    int d = rs * 32 + 8 * q + 4 * hl + j;
                    float v = h[ct][r] * ns_s[d];
                    _Float16 hv = (_Float16)v;
                    H.hx[jj] = hv;
                    L.hx[jj] = (_Float16)((v - (float)hv) * 4096.f);
                }
                int off = (rs * 64 + qp * 32 + hl * 16) ^ xorf;
                *(int4*)(HTH + rowb + off) = H.u;
                *(int4*)(HTL + rowb + off) = L.u;
            }
        }
        __syncthreads();

        // lo pass
        #pragma unroll
        for (int ks = 0; ks < 16; ++ks) {
            uint2 aw = A2[ks];
            union { unsigned u[4]; half8 v; } au;
            au.u[0] = __builtin_amdgcn_perm(0x64646464u, aw.x, 0x05010400u);
            au.u[1] = __builtin_amdgcn_perm(0x64646464u, aw.x, 0x05030402u);
            au.u[2] = __builtin_amdgcn_perm(0x64646464u, aw.y, 0x05010400u);
            au.u[3] = __builtin_amdgcn_perm(0x64646464u, aw.y, 0x05030402u);
            half8 a = au.v - k1024;           // exact: (1024+b) - 1024
            int kb = (ks * 32 + hl * 16) ^ xorf;
            half8 b0 = *(const half8*)(HTL + bR0 + kb);
            half8 b1 = *(const half8*)(HTL + bR0 + 16384 + kb);
            acc0 = __builtin_amdgcn_mfma_f32_32x32x16_f16(a, b0, acc0, 0, 0, 0);
            acc1 = __builtin_amdgcn_mfma_f32_32x32x16_f16(a, b1, acc1, 0, 0, 0);
        }
        #pragma unroll
        for (int i = 0; i < 16; ++i) {
            acc0[i] *= 0.000244140625f;       // 2^-12
            acc1[i] *= 0.000244140625f;
        }
        // hi pass
        #pragma unroll
        for (int ks = 0; ks < 16; ++ks) {
            uint2 aw = A2[ks];
            union { unsigned u[4]; half8 v; } au;
            au.u[0] = __builtin_amdgcn_perm(0x64646464u, aw.x, 0x05010400u);
            au.u[1] = __builtin_amdgcn_perm(0x64646464u, aw.x, 0x05030402u);
            au.u[2] = __builtin_amdgcn_perm(0x64646464u, aw.y, 0x05010400u);
            au.u[3] = __builtin_amdgcn_perm(0x64646464u, aw.y, 0x05030402u);
            half8 a = au.v - k1024;
            int kb = (ks * 32 + hl * 16) ^ xorf;
            half8 b0 = *(const half8*)(HTH + bR0 + kb);
            half8 b1 = *(const half8*)(HTH + bR0 + 16384 + kb);
            acc0 = __builtin_amdgcn_mfma_f32_32x32x16_f16(a, b0, acc0, 0, 0, 0);
            acc1 = __builtin_amdgcn_mfma_f32_32x32x16_f16(a, b1, acc1, 0, 0, 0);
        }

        // epilogue: tanh -> h regs, x (paired cols within this half), rmax
        #pragma unroll
        for (int r = 0; r < 16; ++r) {
            int d = rs * 32 + (r & 3) + 8 * (r >> 2) + 4 * hl;
            float ndv = nd_s[d];
            float t0 = ftanh(acc0[r] * ndv + bias0);
            float t1 = ftanh(acc1[r] * ndv + bias1);
            h[0][r] = t0; h[1][r] = t1;
            size_t xb = (size_t)(vbase + d) * XSTR + (size_t)l * HH + F0 + 2 * l31;
            *(float2*)&x[xb] = make_float2(t0, t1);
            float mv = fmaxf(t0, t1);
            rmax[r] = l ? fmaxf(rmax[r], mv) : mv;
        }
    }

    // ---------------- phase 2: per-node partial max -> nmaxP ----------------
    #pragma unroll
    for (int r = 0; r < 16; ++r) {
        float mv = rmax[r];
        mv = fmaxf(mv, shx<16>(mv));
        mv = fmaxf(mv, shx<8>(mv));
        mv = fmaxf(mv, shx<4>(mv));
        mv = fmaxf(mv, shx<2>(mv));
        mv = fmaxf(mv, shx<1>(mv));
        if (l31 == 0) {
            int d = rs * 32 + (r & 3) + 8 * (r >> 2) + 4 * hl;
            nmaxP[(size_t)half * NN + vbase + d] = mv;
        }
    }
}

// ============ kernel 2: top-30 by rank count (combines the 2 feat-halves) ============
__global__ __launch_bounds__(256) void k_topk(const float* __restrict__ nmaxP,
                                              int* __restrict__ sel) {
    __shared__ float vals[NPER];
    int t = threadIdx.x, g = blockIdx.x, v = g * NPER + t;
    float m = fmaxf(nmaxP[v], nmaxP[NN + v]);
    vals[t] = m;
    __syncthreads();
    int rank = 0;
    for (int u = 0; u < NPER; ++u) {
        float uv = vals[u];
        rank += (uv > m) || (uv == m && u < t);
    }
    if (rank < KK) sel[g * KK + rank] = t;   // local node index
}

// ============ kernel 3: per-row register bitonic sort (DPP/swizzle shuffles) ============
__global__ __launch_bounds__(256) void k_sort(
        const float* __restrict__ x, const int* __restrict__ sel,
        float* __restrict__ pooled) {
    int lane = threadIdx.x & 63, wid = threadIdx.x >> 6;
    int bk = blockIdx.x * 4 + wid;            // row id 0..7679
    int g = bk / KK;
    int n = sel[bk];
    float v[8];
    int e0 = lane * 8;
    if (e0 < DDIM) {
        const float* xr = &x[(size_t)(g * NPER + n) * XSTR + e0];
        float4 a4 = *(const float4*)xr;
        float4 b4 = *(const float4*)(xr + 4);
        v[0] = a4.x; v[1] = a4.y; v[2] = a4.z; v[3] = a4.w;
        v[4] = b4.x; v[5] = b4.y; v[6] = b4.z; v[7] = b4.w;
    } else {
        #pragma unroll
        for (int r = 0; r < 8; ++r) v[r] = INFINITY;
    }
    #define CSW(a, b, u) { float lo = fminf(v[a], v[b]), hi = fmaxf(v[a], v[b]); \
                           v[a] = (u) ? lo : hi; v[b] = (u) ? hi : lo; }
    #define CSWB(up) CSW(0,4,up) CSW(1,5,up) CSW(2,6,up) CSW(3,7,up) \
                     CSW(0,2,up) CSW(1,3,up) CSW(4,6,up) CSW(5,7,up) \
                     CSW(0,1,up) CSW(2,3,up) CSW(4,5,up) CSW(6,7,up)
    #define SHROUND(D, up) { bool km_ = (((lane & (D)) == 0) == (up)); \
        _Pragma("unroll") \
        for (int r_ = 0; r_ < 8; ++r_) { float pv_ = shx<D>(v[r_]); \
            v[r_] = km_ ? fminf(v[r_], pv_) : fmaxf(v[r_], pv_); } }
    // in-register k2=2,4,8
    CSW(0,1,true) CSW(2,3,false) CSW(4,5,true) CSW(6,7,false)
    CSW(0,2,true) CSW(1,3,true) CSW(4,6,false) CSW(5,7,false)
    CSW(0,1,true) CSW(2,3,true) CSW(4,5,false) CSW(6,7,false)
    {
        bool u8 = ((lane & 1) == 0);
        CSW(0,4,u8) CSW(1,5,u8) CSW(2,6,u8) CSW(3,7,u8)
        CSW(0,2,u8) CSW(1,3,u8) CSW(4,6,u8) CSW(5,7,u8)
        CSW(0,1,u8) CSW(2,3,u8) CSW(4,5,u8) CSW(6,7,u8)
    }
    // cross-lane stages k2=16..512
    { bool up = ((lane & 2) == 0);  SHROUND(1, up) CSWB(up) }
    { bool up = ((lane & 4) == 0);  SHROUND(2, up) SHROUND(1, up) CSWB(up) }
    { bool up = ((lane & 8) == 0);  SHROUND(4, up) SHROUND(2, up) SHROUND(1, up) CSWB(up) }
    { bool up = ((lane & 16) == 0); SHROUND(8, up) SHROUND(4, up) SHROUND(2, up) SHROUND(1, up) CSWB(up) }
    { bool up = ((lane & 32) == 0); SHROUND(16, up) SHROUND(8, up) SHROUND(4, up) SHROUND(2, up) SHROUND(1, up) CSWB(up) }
    { bool up = true;               SHROUND(32, up) SHROUND(16, up) SHROUND(8, up) SHROUND(4, up) SHROUND(2, up) SHROUND(1, up) CSWB(up) }
    #undef SHROUND
    #undef CSWB
    #undef CSW
    if (e0 < DDIM) {
        float* pr = pooled + (size_t)bk * DDIM + e0;
        *(float4*)pr = make_float4(v[0], v[1], v[2], v[3]);
        *(float4*)(pr + 4) = make_float4(v[4], v[5], v[6], v[7]);
    }
}

// ============ kernel 4: head (conv1 -> maxpool -> conv2 -> lin1 -> lin2) ============
__global__ __launch_bounds__(512) void k_head(
        const float* __restrict__ pooled,
        const float* __restrict__ w1, const float* __restrict__ b1,
        const float* __restrict__ w2, const float* __restrict__ b2,
        const float* __restrict__ l1w, const float* __restrict__ l1b,
        const float* __restrict__ l2w, const float* __restrict__ l2b,
        float* __restrict__ out) {
    __shared__ float tile[KK * SPD];
    __shared__ float c1s[16 * KK];
    __shared__ float pp[16 * 15];
    __shared__ float fl[352];
    __shared__ float h1[HH];
    int t = threadIdx.x, g = blockIdx.x;
    const float4* pg = (const float4*)(pooled + (size_t)g * KK * DDIM);
    for (int i = t; i < KK * 96; i += 512) {
        int rr = i / 96, f4 = i % 96;
        ((float4*)(tile + rr * SPD))[f4] = pg[rr * 96 + f4];
    }
    __syncthreads();
    if (t < 480) {
        int o = t & 15, k2 = t >> 4;
        const float4* wr = (const float4*)(w1 + o * DDIM);
        const float4* pr = (const float4*)(tile + k2 * SPD);
        float acc = b1[o];
        #pragma unroll 4
        for (int d4 = 0; d4 < 96; ++d4) {
            float4 a = pr[d4], b = wr[d4];
            acc += a.x * b.x + a.y * b.y + a.z * b.z + a.w * b.w;
        }
        c1s[o * KK + k2] = fmaxf(acc, 0.f);
    }
    __syncthreads();
    if (t < 240) {
        int o = t / 15, j = t % 15;
        pp[t] = fmaxf(c1s[o * KK + 2 * j], c1s[o * KK + 2 * j + 1]);
    }
    __syncthreads();
    if (t < 352) {
        int c = t / 11, tt = t % 11;
        float acc = b2[c];
        for (int i = 0; i < 16; ++i) {
            #pragma unroll
            for (int u = 0; u < 5; ++u)
                acc += pp[i * 15 + tt + u] * w2[(c * 16 + i) * 5 + u];
        }
        fl[t] = fmaxf(acc, 0.f);
    }
    __syncthreads();
    if (t < 128) {
        const float4* wr = (const float4*)(l1w + t * 352);
        const float4* fr = (const float4*)fl;
        float acc = l1b[t];
        #pragma unroll 4
        for (int i = 0; i < 88; ++i) {
            float4 a = fr[i], b = wr[i];
            acc += a.x * b.x + a.y * b.y + a.z * b.z + a.w * b.w;
        }
        h1[t] = fmaxf(acc, 0.f);
    }
    __syncthreads();
    if (t < 64) {
        float v2 = h1[t] * l2w[t] + h1[t + 64] * l2w[t + 64];
        for (int s2 = 32; s2 > 0; s2 >>= 1) v2 += __shfl_down(v2, s2);
        if (t == 0) out[g] = v2 + l2b[0];
    }
}

extern "C" void kernel_launch(void* const* d_in, const int* in_sizes, int n_in,
                              void* d_out, int out_size, void* d_ws, size_t ws_size,
                              hipStream_t stream) {
    const int*   z      = (const int*)d_in[0];
    const int*   src    = (const int*)d_in[1];
    const int*   dst    = (const int*)d_in[2];
    const float* zt     = (const float*)d_in[3];
    const float* biases = (const float*)d_in[4];
    const float* w1     = (const float*)d_in[5];
    const float* b1     = (const float*)d_in[6];
    const float* w2     = (const float*)d_in[7];
    const float* b2     = (const float*)d_in[8];
    const float* l1w    = (const float*)d_in[9];
    const float* l1b    = (const float*)d_in[10];
    const float* l2w    = (const float*)d_in[11];
    const float* l2b    = (const float*)d_in[12];
    float* out = (float*)d_out;
    char* ws = (char*)d_ws;
    float* x      = (float*)ws;                                          // 96 MB
    float* nmaxP  = (float*)(ws + (size_t)NN * XSTR * 4);                // 512 KB
    float* pooled = (float*)(ws + (size_t)NN * XSTR * 4 + (size_t)2 * NN * 4);  // 11.8 MB
    int*   sel    = (int*)(ws + (size_t)NN * XSTR * 4 + (size_t)2 * NN * 4
                              + (size_t)BB * KK * DDIM * 4);

    hipFuncSetAttribute((const void*)k_layers,
                        hipFuncAttributeMaxDynamicSharedMemorySize, SMEM_SZ);

    k_layers<<<2 * BB, 512, SMEM_SZ, stream>>>(z, src, dst, zt, biases, x, nmaxP);
    k_topk<<<BB, 256, 0, stream>>>(nmaxP, sel);
    k_sort<<<BB * KK / 4, 256, 0, stream>>>(x, sel, pooled);
    k_head<<<BB, 512, 0, stream>>>(pooled, w1, b1, w2, b2, l1w, l1b, l2w, l2b, out);
}

// Round 17
// 115.427 us; speedup vs baseline: 1.4066x; 1.4066x over previous
//
#include <hip/hip_runtime.h>
#include <math.h>

#define BB   256
#define NPER 256
#define NN   (BB*NPER)
#define HH   128
#define DDIM 384
#define KK   30
#define SPD  388
#define ASTR 264          // 66 dwords -> 2-way bank alias (free)
#define ABYTES 67584
#define XSTR 384          // x holds all 3 layers (paired cols, sort-invariant)

#define NSOFF  67584
#define NDOFF  68608
#define SCROFF 69632      // 3072B: degi, dego, z_s
#define SMEM_SZ 72704     // <= 80K -> 2 blocks/CU

typedef _Float16 half8 __attribute__((ext_vector_type(8)));
typedef float f32x16 __attribute__((ext_vector_type(16)));

__device__ __forceinline__ float ftanh(float x) {
    float ax = fabsf(x);
    float e = __expf(-2.f * ax);
    float r = (1.f - e) / (1.f + e);
    return copysignf(r, x);
}

// swap bits 2<->3: MFMA k-group permutation (validated bit-exact r6-r16)
__device__ __forceinline__ int sig(int s) {
    return (s & ~12) | ((s & 4) << 1) | ((s & 8) >> 1);
}

// cross-lane xor exchange; DPP for 1/2/8 (VALU pipe), ds_swizzle 4/16, shfl 32.
template <int D>
__device__ __forceinline__ float shx(float v) {
    int xx = __float_as_int(v);
    int r;
    if constexpr (D == 1)       r = __builtin_amdgcn_update_dpp(0, xx, 0xB1, 0xF, 0xF, true);   // quad_perm [1,0,3,2]
    else if constexpr (D == 2)  r = __builtin_amdgcn_update_dpp(0, xx, 0x4E, 0xF, 0xF, true);   // quad_perm [2,3,0,1]
    else if constexpr (D == 8)  r = __builtin_amdgcn_update_dpp(0, xx, 0x128, 0xF, 0xF, true);  // row_ror:8 == xor8
    else if constexpr (D == 4)  r = __builtin_amdgcn_ds_swizzle(xx, 0x101F);                     // xor4
    else if constexpr (D == 16) r = __builtin_amdgcn_ds_swizzle(xx, 0x401F);                     // xor16
    else                        return __shfl_xor(v, D, 64);
    return __int_as_float(r);
}

// ============ kernel 1: GraphConv layers, feature-split (2 blocks/graph) ============
// __launch_bounds__ 2nd arg = min BLOCKS/CU (CUDA semantics — r10/r11/r16 evidence:
// (512,2)->124 regs, (512,4)->64 regs, (1024,4)->64 regs). (512,2) => 128-reg cap,
// and 72.7K LDS => 2 blocks/CU = 4 waves/SIMD actually resident.
__global__ __launch_bounds__(512, 2) void k_layers(
        const int* __restrict__ z, const int* __restrict__ src, const int* __restrict__ dst,
        const float* __restrict__ zt, const float* __restrict__ biases,
        float* __restrict__ x, float* __restrict__ nmaxP) {
    extern __shared__ char smem[];
    unsigned char* As = (unsigned char*)smem;          // 256 x 264 u8 (phase 0 only)
    char* HTH = smem;                                  // 64 rows x 512B f16 hi (overlays As)
    char* HTL = smem + 32768;                          // 64 rows x 512B f16 lo
    float* ns_s = (float*)(smem + NSOFF);
    float* nd_s = (float*)(smem + NDOFF);
    int*   scr  = (int*)(smem + SCROFF);
    int* degi = scr; int* dego = scr + 256; int* z_s = scr + 512;

    const int t = threadIdx.x;
    const int g = blockIdx.x >> 1, half = blockIdx.x & 1;
    const int vbase = g * NPER, F0 = half * 64;
    const int l31 = t & 31, hl = (t >> 5) & 1, rs = t >> 6;
    const int xorf = l31 << 4;
    const int aRow = (rs * 32 + l31) * ASTR;
    const int bR0  = l31 * 512;                        // ct=0 rows; ct=1 at +16384

    // ---------------- phase 0: build A (LDS) + histograms ----------------
    {
        int4 zz = {0, 0, 0, 0};
        for (int i = t; i < ABYTES / 16; i += 512) ((int4*)smem)[i] = zz;
    }
    if (t < 256) { degi[t] = 0; dego[t] = 0; z_s[t] = z[vbase + t]; }
    __syncthreads();
    for (int e = t; e < 4096; e += 512) {
        int s = src[g * 4096 + e] & 255;      // local ids by construction
        int d = dst[g * 4096 + e] & 255;
        atomicAdd(&dego[s], 1);
        atomicAdd(&degi[d], 1);
        int off = d * ASTR + sig(s);
        atomicAdd((unsigned*)(As + (off & ~3)), 1u << ((off & 3) * 8));
    }
    __syncthreads();
    if (t < 256) {
        ns_s[t] = rsqrtf((float)max(dego[t], 1));
        nd_s[t] = rsqrtf((float)max(degi[t], 1));
    }
    // h0 (unscaled) into C-layout registers: this block's 64 feats
    float h[2][16];
    #pragma unroll
    for (int ct = 0; ct < 2; ++ct) {
        #pragma unroll
        for (int r = 0; r < 16; ++r) {
            int d = rs * 32 + (r & 3) + 8 * (r >> 2) + 4 * hl;
            h[ct][r] = zt[(size_t)z_s[d] * HH + F0 + ct * 32 + l31];
        }
    }
    // A slice u8-packed into 32 regs (As LDS dies after this; HT overlays)
    uint2 A2[16];
    #pragma unroll
    for (int ks = 0; ks < 16; ++ks)
        A2[ks] = *(const uint2*)(As + aRow + ks * 16 + hl * 8);

    float rmax[16];
    const half8 k1024 = {(_Float16)1024.f, (_Float16)1024.f, (_Float16)1024.f, (_Float16)1024.f,
                         (_Float16)1024.f, (_Float16)1024.f, (_Float16)1024.f, (_Float16)1024.f};

    // ---------------- phase 1: 3 GraphConv layers, 2-term fp16 split MFMA ----------------
    for (int l = 0; l < 3; ++l) {
        float bias0 = biases[l * HH + F0 + l31];
        float bias1 = biases[l * HH + F0 + 32 + l31];
        f32x16 acc0 = {}, acc1 = {};

        __syncthreads();                      // prior kloop reads / A2 loads done
        // write BOTH split terms of (h * ns)
        #pragma unroll
        for (int ct = 0; ct < 2; ++ct) {
            int rowb = (ct * 32 + l31) * 512;
            #pragma unroll
            for (int qp = 0; qp < 2; ++qp) {
                union { _Float16 hx[8]; int4 u; } H, L;
                #pragma unroll
                for (int jj = 0; jj < 8; ++jj) {
                    int q = 2 * qp + (jj >> 2), j = jj & 3;
                    int r = 4 * q + j;
                    int d = rs * 32 + 8 * q + 4 * hl + j;
                    float v = h[ct][r] * ns_s[d];
                    _Float16 hv = (_Float16)v;
                    H.hx[jj] = hv;
                    L.hx[jj] = (_Float16)((v - (float)hv) * 4096.f);
                }
                int off = (rs * 64 + qp * 32 + hl * 16) ^ xorf;
                *(int4*)(HTH + rowb + off) = H.u;
                *(int4*)(HTL + rowb + off) = L.u;
            }
        }
        __syncthreads();

        // lo pass
        #pragma unroll
        for (int ks = 0; ks < 16; ++ks) {
            uint2 aw = A2[ks];
            union { unsigned u[4]; half8 v; } au;
            au.u[0] = __builtin_amdgcn_perm(0x64646464u, aw.x, 0x05010400u);
            au.u[1] = __builtin_amdgcn_perm(0x64646464u, aw.x, 0x05030402u);
            au.u[2] = __builtin_amdgcn_perm(0x64646464u, aw.y, 0x05010400u);
            au.u[3] = __builtin_amdgcn_perm(0x64646464u, aw.y, 0x05030402u);
            half8 a = au.v - k1024;           // exact: (1024+b) - 1024
            int kb = (ks * 32 + hl * 16) ^ xorf;
            half8 b0 = *(const half8*)(HTL + bR0 + kb);
            half8 b1 = *(const half8*)(HTL + bR0 + 16384 + kb);
            acc0 = __builtin_amdgcn_mfma_f32_32x32x16_f16(a, b0, acc0, 0, 0, 0);
            acc1 = __builtin_amdgcn_mfma_f32_32x32x16_f16(a, b1, acc1, 0, 0, 0);
        }
        #pragma unroll
        for (int i = 0; i < 16; ++i) {
            acc0[i] *= 0.000244140625f;       // 2^-12
            acc1[i] *= 0.000244140625f;
        }
        // hi pass
        #pragma unroll
        for (int ks = 0; ks < 16; ++ks) {
            uint2 aw = A2[ks];
            union { unsigned u[4]; half8 v; } au;
            au.u[0] = __builtin_amdgcn_perm(0x64646464u, aw.x, 0x05010400u);
            au.u[1] = __builtin_amdgcn_perm(0x64646464u, aw.x, 0x05030402u);
            au.u[2] = __builtin_amdgcn_perm(0x64646464u, aw.y, 0x05010400u);
            au.u[3] = __builtin_amdgcn_perm(0x64646464u, aw.y, 0x05030402u);
            half8 a = au.v - k1024;
            int kb = (ks * 32 + hl * 16) ^ xorf;
            half8 b0 = *(const half8*)(HTH + bR0 + kb);
            half8 b1 = *(const half8*)(HTH + bR0 + 16384 + kb);
            acc0 = __builtin_amdgcn_mfma_f32_32x32x16_f16(a, b0, acc0, 0, 0, 0);
            acc1 = __builtin_amdgcn_mfma_f32_32x32x16_f16(a, b1, acc1, 0, 0, 0);
        }

        // epilogue: tanh -> h regs, x (paired cols within this half), rmax
        #pragma unroll
        for (int r = 0; r < 16; ++r) {
            int d = rs * 32 + (r & 3) + 8 * (r >> 2) + 4 * hl;
            float ndv = nd_s[d];
            float t0 = ftanh(acc0[r] * ndv + bias0);
            float t1 = ftanh(acc1[r] * ndv + bias1);
            h[0][r] = t0; h[1][r] = t1;
            size_t xb = (size_t)(vbase + d) * XSTR + (size_t)l * HH + F0 + 2 * l31;
            *(float2*)&x[xb] = make_float2(t0, t1);
            float mv = fmaxf(t0, t1);
            rmax[r] = l ? fmaxf(rmax[r], mv) : mv;
        }
    }

    // ---------------- phase 2: per-node partial max -> nmaxP ----------------
    #pragma unroll
    for (int r = 0; r < 16; ++r) {
        float mv = rmax[r];
        mv = fmaxf(mv, shx<16>(mv));
        mv = fmaxf(mv, shx<8>(mv));
        mv = fmaxf(mv, shx<4>(mv));
        mv = fmaxf(mv, shx<2>(mv));
        mv = fmaxf(mv, shx<1>(mv));
        if (l31 == 0) {
            int d = rs * 32 + (r & 3) + 8 * (r >> 2) + 4 * hl;
            nmaxP[(size_t)half * NN + vbase + d] = mv;
        }
    }
}

// ============ kernel 2: top-30 by rank count (combines the 2 feat-halves) ============
__global__ __launch_bounds__(256) void k_topk(const float* __restrict__ nmaxP,
                                              int* __restrict__ sel) {
    __shared__ float vals[NPER];
    int t = threadIdx.x, g = blockIdx.x, v = g * NPER + t;
    float m = fmaxf(nmaxP[v], nmaxP[NN + v]);
    vals[t] = m;
    __syncthreads();
    int rank = 0;
    for (int u = 0; u < NPER; ++u) {
        float uv = vals[u];
        rank += (uv > m) || (uv == m && u < t);
    }
    if (rank < KK) sel[g * KK + rank] = t;   // local node index
}

// ============ kernel 3: per-row register bitonic sort (DPP/swizzle shuffles) ============
__global__ __launch_bounds__(256) void k_sort(
        const float* __restrict__ x, const int* __restrict__ sel,
        float* __restrict__ pooled) {
    int lane = threadIdx.x & 63, wid = threadIdx.x >> 6;
    int bk = blockIdx.x * 4 + wid;            // row id 0..7679
    int g = bk / KK;
    int n = sel[bk];
    float v[8];
    int e0 = lane * 8;
    if (e0 < DDIM) {
        const float* xr = &x[(size_t)(g * NPER + n) * XSTR + e0];
        float4 a4 = *(const float4*)xr;
        float4 b4 = *(const float4*)(xr + 4);
        v[0] = a4.x; v[1] = a4.y; v[2] = a4.z; v[3] = a4.w;
        v[4] = b4.x; v[5] = b4.y; v[6] = b4.z; v[7] = b4.w;
    } else {
        #pragma unroll
        for (int r = 0; r < 8; ++r) v[r] = INFINITY;
    }
    #define CSW(a, b, u) { float lo = fminf(v[a], v[b]), hi = fmaxf(v[a], v[b]); \
                           v[a] = (u) ? lo : hi; v[b] = (u) ? hi : lo; }
    #define CSWB(up) CSW(0,4,up) CSW(1,5,up) CSW(2,6,up) CSW(3,7,up) \
                     CSW(0,2,up) CSW(1,3,up) CSW(4,6,up) CSW(5,7,up) \
                     CSW(0,1,up) CSW(2,3,up) CSW(4,5,up) CSW(6,7,up)
    #define SHROUND(D, up) { bool km_ = (((lane & (D)) == 0) == (up)); \
        _Pragma("unroll") \
        for (int r_ = 0; r_ < 8; ++r_) { float pv_ = shx<D>(v[r_]); \
            v[r_] = km_ ? fminf(v[r_], pv_) : fmaxf(v[r_], pv_); } }
    // in-register k2=2,4,8
    CSW(0,1,true) CSW(2,3,false) CSW(4,5,true) CSW(6,7,false)
    CSW(0,2,true) CSW(1,3,true) CSW(4,6,false) CSW(5,7,false)
    CSW(0,1,true) CSW(2,3,true) CSW(4,5,false) CSW(6,7,false)
    {
        bool u8 = ((lane & 1) == 0);
        CSW(0,4,u8) CSW(1,5,u8) CSW(2,6,u8) CSW(3,7,u8)
        CSW(0,2,u8) CSW(1,3,u8) CSW(4,6,u8) CSW(5,7,u8)
        CSW(0,1,u8) CSW(2,3,u8) CSW(4,5,u8) CSW(6,7,u8)
    }
    // cross-lane stages k2=16..512
    { bool up = ((lane & 2) == 0);  SHROUND(1, up) CSWB(up) }
    { bool up = ((lane & 4) == 0);  SHROUND(2, up) SHROUND(1, up) CSWB(up) }
    { bool up = ((lane & 8) == 0);  SHROUND(4, up) SHROUND(2, up) SHROUND(1, up) CSWB(up) }
    { bool up = ((lane & 16) == 0); SHROUND(8, up) SHROUND(4, up) SHROUND(2, up) SHROUND(1, up) CSWB(up) }
    { bool up = ((lane & 32) == 0); SHROUND(16, up) SHROUND(8, up) SHROUND(4, up) SHROUND(2, up) SHROUND(1, up) CSWB(up) }
    { bool up = true;               SHROUND(32, up) SHROUND(16, up) SHROUND(8, up) SHROUND(4, up) SHROUND(2, up) SHROUND(1, up) CSWB(up) }
    #undef SHROUND
    #undef CSWB
    #undef CSW
    if (e0 < DDIM) {
        float* pr = pooled + (size_t)bk * DDIM + e0;
        *(float4*)pr = make_float4(v[0], v[1], v[2], v[3]);
        *(float4*)(pr + 4) = make_float4(v[4], v[5], v[6], v[7]);
    }
}

// ============ kernel 4: head (conv1 -> maxpool -> conv2 -> lin1 -> lin2) ============
__global__ __launch_bounds__(512) void k_head(
        const float* __restrict__ pooled,
        const float* __restrict__ w1, const float* __restrict__ b1,
        const float* __restrict__ w2, const float* __restrict__ b2,
        const float* __restrict__ l1w, const float* __restrict__ l1b,
        const float* __restrict__ l2w, const float* __restrict__ l2b,
        float* __restrict__ out) {
    __shared__ float tile[KK * SPD];
    __shared__ float c1s[16 * KK];
    __shared__ float pp[16 * 15];
    __shared__ float fl[352];
    __shared__ float h1[HH];
    int t = threadIdx.x, g = blockIdx.x;
    const float4* pg = (const float4*)(pooled + (size_t)g * KK * DDIM);
    for (int i = t; i < KK * 96; i += 512) {
        int rr = i / 96, f4 = i % 96;
        ((float4*)(tile + rr * SPD))[f4] = pg[rr * 96 + f4];
    }
    __syncthreads();
    if (t < 480) {
        int o = t & 15, k2 = t >> 4;
        const float4* wr = (const float4*)(w1 + o * DDIM);
        const float4* pr = (const float4*)(tile + k2 * SPD);
        float acc = b1[o];
        #pragma unroll 4
        for (int d4 = 0; d4 < 96; ++d4) {
            float4 a = pr[d4], b = wr[d4];
            acc += a.x * b.x + a.y * b.y + a.z * b.z + a.w * b.w;
        }
        c1s[o * KK + k2] = fmaxf(acc, 0.f);
    }
    __syncthreads();
    if (t < 240) {
        int o = t / 15, j = t % 15;
        pp[t] = fmaxf(c1s[o * KK + 2 * j], c1s[o * KK + 2 * j + 1]);
    }
    __syncthreads();
    if (t < 352) {
        int c = t / 11, tt = t % 11;
        float acc = b2[c];
        for (int i = 0; i < 16; ++i) {
            #pragma unroll
            for (int u = 0; u < 5; ++u)
                acc += pp[i * 15 + tt + u] * w2[(c * 16 + i) * 5 + u];
        }
        fl[t] = fmaxf(acc, 0.f);
    }
    __syncthreads();
    if (t < 128) {
        const float4* wr = (const float4*)(l1w + t * 352);
        const float4* fr = (const float4*)fl;
        float acc = l1b[t];
        #pragma unroll 4
        for (int i = 0; i < 88; ++i) {
            float4 a = fr[i], b = wr[i];
            acc += a.x * b.x + a.y * b.y + a.z * b.z + a.w * b.w;
        }
        h1[t] = fmaxf(acc, 0.f);
    }
    __syncthreads();
    if (t < 64) {
        float v2 = h1[t] * l2w[t] + h1[t + 64] * l2w[t + 64];
        for (int s2 = 32; s2 > 0; s2 >>= 1) v2 += __shfl_down(v2, s2);
        if (t == 0) out[g] = v2 + l2b[0];
    }
}

extern "C" void kernel_launch(void* const* d_in, const int* in_sizes, int n_in,
                              void* d_out, int out_size, void* d_ws, size_t ws_size,
                              hipStream_t stream) {
    const int*   z      = (const int*)d_in[0];
    const int*   src    = (const int*)d_in[1];
    const int*   dst    = (const int*)d_in[2];
    const float* zt     = (const float*)d_in[3];
    const float* biases = (const float*)d_in[4];
    const float* w1     = (const float*)d_in[5];
    const float* b1     = (const float*)d_in[6];
    const float* w2     = (const float*)d_in[7];
    const float* b2     = (const float*)d_in[8];
    const float* l1w    = (const float*)d_in[9];
    const float* l1b    = (const float*)d_in[10];
    const float* l2w    = (const float*)d_in[11];
    const float* l2b    = (const float*)d_in[12];
    float* out = (float*)d_out;
    char* ws = (char*)d_ws;
    float* x      = (float*)ws;                                          // 96 MB
    float* nmaxP  = (float*)(ws + (size_t)NN * XSTR * 4);                // 512 KB
    float* pooled = (float*)(ws + (size_t)NN * XSTR * 4 + (size_t)2 * NN * 4);  // 11.8 MB
    int*   sel    = (int*)(ws + (size_t)NN * XSTR * 4 + (size_t)2 * NN * 4
                              + (size_t)BB * KK * DDIM * 4);

    hipFuncSetAttribute((const void*)k_layers,
                        hipFuncAttributeMaxDynamicSharedMemorySize, SMEM_SZ);

    k_layers<<<2 * BB, 512, SMEM_SZ, stream>>>(z, src, dst, zt, biases, x, nmaxP);
    k_topk<<<BB, 256, 0, stream>>>(nmaxP, sel);
    k_sort<<<BB * KK / 4, 256, 0, stream>>>(x, sel, pooled);
    k_head<<<BB, 512, 0, stream>>>(pooled, w1, b1, w2, b2, l1w, l1b, l2w, l2b, out);
}